// Round 12
// baseline (242.066 us; speedup 1.0000x reference)
//
#include <hip/hip_runtime.h>
#include <hip/hip_bf16.h>
#include <cstdint>
#include <cstddef>

typedef float  f32x4  __attribute__((ext_vector_type(4)));
typedef __bf16 bf16x8 __attribute__((ext_vector_type(8)));
typedef __bf16 bf16x4 __attribute__((ext_vector_type(4)));

// Problem constants
// B=4, H=W=256, Cin=16, P=8, DIM=16, HEADS=4
// patches: 4*32*32 = 4096, K1 = 8*8*16 = 1024, N1 = 3*4096 = 12288
// Z: [4096, 4096], Wout: [4096, 1024]

#define GLOAD_LDS16(gp, lp)                                                     \
    __builtin_amdgcn_global_load_lds(                                           \
        (const __attribute__((address_space(1))) void*)(gp),                    \
        (__attribute__((address_space(3))) void*)(lp), 16, 0, 0)

#define MFMA16(d, a, b) d = __builtin_amdgcn_mfma_f32_16x16x32_bf16(a, b, d, 0, 0, 0)

// s_barrier with compile-time memory ordering (raw builtin is NOT a fence)
#define BAR() asm volatile("s_barrier" ::: "memory")

// ---------------------------------------------------------------------------
// merged prep kernel: one dispatch, block-range dispatch to 4 sub-kernels.
//  [0,4096)        im2col   x -> Xb
//  [4096,4864)     wqkvT    Wq/Wk/Wv -> WqkvT (permuted, transposed, bf16)
//  [4864,4912)     biasperm bq/bk/bv -> bperm
//  [4912,5424)     woutT    Wout -> WoutT (col-permuted, transposed, bf16)
// ---------------------------------------------------------------------------
__global__ __launch_bounds__(256) void k_prep(const float* __restrict__ x,
                                              const float* __restrict__ Wq,
                                              const float* __restrict__ Wk,
                                              const float* __restrict__ Wv,
                                              const float* __restrict__ bq,
                                              const float* __restrict__ bk,
                                              const float* __restrict__ bv,
                                              const float* __restrict__ Wo,
                                              __bf16* __restrict__ Xb,
                                              __bf16* __restrict__ WT,
                                              float* __restrict__ bp,
                                              __bf16* __restrict__ WoT)
{
    __shared__ float smem[64 * 261];     // 66816 B; reused by wqkvT/woutT
    const int blk = (int)blockIdx.x;
    const int t = threadIdx.x;

    if (blk < 4096) {
        // ---- im2col ----
        const int p = blk;
        const int b = p >> 10, hh = (p >> 5) & 31, ww = p & 31;
        const int e = t * 4;
        const int c = e & 15, ij = e >> 4;
        const int i = ij >> 3, j = ij & 7;
        const size_t src = ((((size_t)(b * 256 + hh * 8 + i)) * 256) + (ww * 8 + j)) * 16 + c;
        f32x4 v = *(const f32x4*)(x + src);
        bf16x4 o;
        o[0] = (__bf16)v[0]; o[1] = (__bf16)v[1]; o[2] = (__bf16)v[2]; o[3] = (__bf16)v[3];
        *(bf16x4*)(Xb + (size_t)p * 1024 + e) = o;
    } else if (blk < 4864) {
        // ---- wqkvT ----
        int q = blk - 4096;
        const int kb = q & 15;   q >>= 4;
        const int ch = q & 15;   q >>= 4;
        const int s  = q;
        const int k0 = kb * 64;
        const float* __restrict__ W = (s == 0) ? Wq : (s == 1) ? Wk : Wv;
#pragma unroll
        for (int rep = 0; rep < 16; rep++) {
            const int idx = rep * 256 + t;
            const int kl = idx >> 6, col4 = (idx & 63) * 4;
            const f32x4 v = *(const f32x4*)(W + (size_t)(k0 + kl) * 4096 + ch * 256 + col4);
            smem[kl * 261 + col4 + 0] = v[0];
            smem[kl * 261 + col4 + 1] = v[1];
            smem[kl * 261 + col4 + 2] = v[2];
            smem[kl * 261 + col4 + 3] = v[3];
        }
        __syncthreads();
        const size_t nbase = (size_t)s * 4096 + ch * 64;
#pragma unroll
        for (int rep = 0; rep < 64; rep++) {
            const int idx = rep * 256 + t;
            const int kl = idx & 63;
            const int rest = idx >> 6;
            const int p = rest & 63, h = rest >> 6;
            WT[(nbase + h * 1024 + p) * 1024 + k0 + kl] = (__bf16)smem[kl * 261 + p * 4 + h];
        }
    } else if (blk < 4912) {
        // ---- biasperm ----
        const int n = (blk - 4864) * 256 + t;
        const int s = n >> 12;
        const int r = n & 4095;
        const int head = r >> 10, c = (r >> 6) & 15, pp = r & 63;
        const float* __restrict__ b = (s == 0) ? bq : (s == 1) ? bk : bv;
        bp[n] = b[c * 256 + pp * 4 + head];
    } else {
        // ---- woutT ----
        const int q = blk - 4912;
        const int n0 = (q & 15) * 64;
        const int k0 = (q >> 4) * 128;
        const int ch = n0 >> 6;
#pragma unroll
        for (int rep = 0; rep < 32; rep++) {
            const int idx = rep * 256 + t;
            const int kl = idx >> 6, nn = idx & 63;
            smem[nn * 129 + kl] = Wo[(size_t)(k0 + kl) * 1024 + n0 + nn];
        }
        __syncthreads();
#pragma unroll
        for (int rep = 0; rep < 32; rep++) {
            const int idx = rep * 256 + t;
            const int nn = idx >> 7, kl = idx & 127;
            const int no = ((nn >> 3) & 7) * 128 + (nn & 7) * 16 + ch;
            WoT[(size_t)no * 4096 + k0 + kl] = (__bf16)smem[nn * 129 + kl];
        }
    }
}

// ---------------------------------------------------------------------------
// 128x128 2-phase bf16 GEMM, 256 thr = 4 waves (2x2), wave tile 64x64,
// BK=64, dbuf LDS 64 KB -> 2 blocks/CU (inter-block TLP hides drains).
//  p1: read b(t)[8] + a1(t)[4]; stage B(t+1)[4]; 16 MFMA (a0 x b);
//      vmcnt(4) retires A(t+1)   [FIFO: A(t+1)@p2(t-1):4, B(t+1)@p1(t):4]
//  p2: read a0(t+1)[4]; stage A(t+2)[4]; 16 MFMA (a1 x b);
//      vmcnt(stA?4:0) retires B(t+1).
// Same XOR swizzle as before (all row offsets multiples of 16 -> same lswz).
// ---------------------------------------------------------------------------
__device__ __forceinline__ void stage128(const __bf16* __restrict__ mat,
                                         const int gRow0, const int K,
                                         const int k0, __bf16* lds, const int t)
{
    const int wbase = t & ~63;                       // wave-uniform lane base
#pragma unroll
    for (int r = 0; r < 4; r++) {
        const int idx = r * 256 + t;                 // 0..1023 (16B chunks)
        const int row = idx >> 3;                    // 0..127
        const int colb = ((t & 7) << 4) ^ ((row & 7) << 4);
        const char* gp = (const char*)(mat + (size_t)(gRow0 + row) * K + k0) + colb;
        GLOAD_LDS16(gp, (char*)lds + (size_t)(r * 256 + wbase) * 16);
    }
}

__global__ __launch_bounds__(256, 2) void gemm128(const __bf16* __restrict__ A,
                                                  const __bf16* __restrict__ Bt,
                                                  __bf16* __restrict__ C,
                                                  const float* __restrict__ bias,
                                                  const int M, const int N,
                                                  const int K, const int nby)
{
    __shared__ __bf16 As[2][128 * 64];
    __shared__ __bf16 Bs[2][128 * 64];

    const int t = threadIdx.x;
    const int l = t & 63, w = t >> 6;
    const int wr = w >> 1, wc = w & 1;               // 2 x 2 wave grid

    // XCD-aware bijective swizzle; column-major (bm fast) for B L2 locality
    const int nwg = (int)gridDim.x, cpx = nwg >> 3;
    const int bid = (int)blockIdx.x;
    const int sbid = (bid & 7) * cpx + (bid >> 3);
    const int bm = sbid % nby, bn = sbid / nby;
    const int row0 = bm * 128, col0 = bn * 128;

    const int lrow = l & 15;
    const int lkb  = (l >> 4) << 4;                  // k-group byte offset
    const int lswz = (l & 7) << 4;
    const int ce0 = ((0  + lkb) ^ lswz) >> 1;        // element col, kk=0
    const int ce1 = ((64 + lkb) ^ lswz) >> 1;        // element col, kk=1

    const int arow = wr * 64 + lrow;                 // + mi*16, mi=0..3
    const int brow = wc * 64 + lrow;                 // + ni*16, ni=0..3

    const int NT = K >> 6;
    f32x4 acc[4][4] = {};
    bf16x8 a0[2][2], a1[2][2], b[4][2];

    // prologue: A(0),A(1),B(0) staged; drain; pre-read a0(0)
    stage128(A,  row0, K, 0,  As[0], t);
    stage128(A,  row0, K, 64, As[1], t);
    stage128(Bt, col0, K, 0,  Bs[0], t);
    asm volatile("s_waitcnt vmcnt(0)" ::: "memory");
    BAR();
#pragma unroll
    for (int mi = 0; mi < 2; ++mi) {
        const int rr = (arow + mi * 16) * 64;
        a0[mi][0] = *(const bf16x8*)&As[0][rr + ce0];
        a0[mi][1] = *(const bf16x8*)&As[0][rr + ce1];
    }

    int cur = 0;
    for (int it = 0; it < NT; ++it) {
        const __bf16* AsC = As[cur];
        const __bf16* AsN = As[cur ^ 1];
        const __bf16* BsC = Bs[cur];
        __bf16* BsN = Bs[cur ^ 1];
        const bool stB = (it + 1 < NT);      // stage B(t+1) -> Bs[cur^1]
        const bool stA = (it + 2 < NT);      // stage A(t+2) -> As[cur]
        const bool pfA = (it + 1 < NT);      // prefetch a0(t+1) from As[cur^1]
        const int kB = (it + 1) << 6;
        const int kA = (it + 2) << 6;

        // ---- p1: acc[0..1][*] += a0 x b ; stage B(t+1) ; F1 -------------
        BAR();
#pragma unroll
        for (int ni = 0; ni < 4; ++ni) {
            const int rr = (brow + ni * 16) * 64;
            b[ni][0] = *(const bf16x8*)&BsC[rr + ce0];
            b[ni][1] = *(const bf16x8*)&BsC[rr + ce1];
        }
#pragma unroll
        for (int mi = 0; mi < 2; ++mi) {
            const int rr = (arow + 32 + mi * 16) * 64;
            a1[mi][0] = *(const bf16x8*)&AsC[rr + ce0];
            a1[mi][1] = *(const bf16x8*)&AsC[rr + ce1];
        }
        if (stB) stage128(Bt, col0, K, kB, BsN, t);
        __builtin_amdgcn_s_setprio(1);
#pragma unroll
        for (int mi = 0; mi < 2; ++mi)
#pragma unroll
            for (int ni = 0; ni < 4; ++ni) {
                MFMA16(acc[mi][ni], a0[mi][0], b[ni][0]);
                MFMA16(acc[mi][ni], a0[mi][1], b[ni][1]);
            }
        __builtin_amdgcn_s_setprio(0);
        if (pfA)   // A(t+1) resident before p2's prefetch reads
            asm volatile("s_waitcnt vmcnt(4)" ::: "memory");

        // ---- p2: acc[2..3][*] += a1 x b ; prefetch a0(t+1) ; stage A(t+2)
        BAR();
        if (pfA) {
#pragma unroll
            for (int mi = 0; mi < 2; ++mi) {
                const int rr = (arow + mi * 16) * 64;
                a0[mi][0] = *(const bf16x8*)&AsN[rr + ce0];
                a0[mi][1] = *(const bf16x8*)&AsN[rr + ce1];
            }
        }
        if (stA) stage128(A, row0, K, kA, As[cur], t);
        __builtin_amdgcn_s_setprio(1);
#pragma unroll
        for (int mi = 0; mi < 2; ++mi)
#pragma unroll
            for (int ni = 0; ni < 4; ++ni) {
                MFMA16(acc[2 + mi][ni], a1[mi][0], b[ni][0]);
                MFMA16(acc[2 + mi][ni], a1[mi][1], b[ni][1]);
            }
        __builtin_amdgcn_s_setprio(0);
        if (stB) {  // B(t+1) resident before next p1's b reads
            if (stA) asm volatile("s_waitcnt vmcnt(4)" ::: "memory");
            else     asm volatile("s_waitcnt vmcnt(0)" ::: "memory");
        }

        cur ^= 1;
    }

    // epilogue: C += bias, bf16
    const int rbase = row0 + wr * 64;
    const int cbase = col0 + wc * 64;
    const int jr = (l >> 4) * 4;
#pragma unroll
    for (int m = 0; m < 4; ++m)
#pragma unroll
        for (int n = 0; n < 4; ++n) {
            const int cw = cbase + n * 16 + lrow;
            const float bsv = bias[cw];
#pragma unroll
            for (int j = 0; j < 4; ++j) {
                const int rw = rbase + m * 16 + jr + j;
                C[(size_t)rw * N + cw] = (__bf16)(acc[m][n][j] + bsv);
            }
        }
}

// ---------------------------------------------------------------------------
// gemm2 split-K=4: 128x128 glds GEMM, 1024 blocks = (bm 32, ks 4, bn 8).
// Each block does K/4 = 1024 and stores fp32 partial P[ks][4096][1024].
// 4 blocks/CU resident -> TLP hides the 2-phase vmcnt(0) drains.
// ---------------------------------------------------------------------------
template <int BN>
__global__ __launch_bounds__(256, 4) void gemm_splitk(const __bf16* __restrict__ A,
                                                      const __bf16* __restrict__ Bt,
                                                      float* __restrict__ Pout,
                                                      const int K, const int kc)
{
    constexpr int BM  = 128, BK = 64;
    constexpr int NF  = BN / 32;
    constexpr int APW = (BM * BK / 512) / 4;
    constexpr int BPW = (BN * BK / 512) / 4;
    __shared__ __bf16 As[BM * BK];
    __shared__ __bf16 Bs[BN * BK];

    const int t = threadIdx.x;
    const int l = t & 63, w = t >> 6;

    const int nwg  = (int)gridDim.x;
    const int cpx  = nwg >> 3;
    const int bid  = (int)blockIdx.x;
    const int sbid = (bid & 7) * cpx + (bid >> 3);
    const int bm = sbid >> 5;                // 0..31
    const int ks = (sbid >> 3) & 3;          // 0..3
    const int bn = sbid & 7;                 // 0..7
    const int row0 = bm * BM, col0 = bn * BN;
    const int kstart = ks * kc;

    const int wr = w >> 1, wc = w & 1;
    const int lr = l & 15;
    const int lk = (l >> 4) * 8;
    const int srow = l >> 3;
    const int scol = (l & 7) * 8;

    f32x4 acc[4][NF] = {};

    for (int k0 = kstart; k0 < kstart + kc; k0 += BK) {
        __syncthreads();
#pragma unroll
        for (int p = 0; p < APW; p++) {
            const int chunk = w * APW + p;
            const __bf16* gp = A + (size_t)(row0 + chunk * 8 + srow) * K + k0 + scol;
            GLOAD_LDS16(gp, &As[chunk * 512]);
        }
#pragma unroll
        for (int p = 0; p < BPW; p++) {
            const int chunk = w * BPW + p;
            const __bf16* gp = Bt + (size_t)(col0 + chunk * 8 + srow) * K + k0 + scol;
            GLOAD_LDS16(gp, &Bs[chunk * 512]);
        }
        __syncthreads();
#pragma unroll
        for (int kk = 0; kk < 2; kk++) {
            bf16x8 af[4], bfr[NF];
#pragma unroll
            for (int m = 0; m < 4; m++)
                af[m] = *(const bf16x8*)&As[(wr * 64 + m * 16 + lr) * BK + kk * 32 + lk];
#pragma unroll
            for (int n = 0; n < NF; n++)
                bfr[n] = *(const bf16x8*)&Bs[(wc * (BN / 2) + n * 16 + lr) * BK + kk * 32 + lk];
#pragma unroll
            for (int m = 0; m < 4; m++)
#pragma unroll
                for (int n = 0; n < NF; n++)
                    acc[m][n] = __builtin_amdgcn_mfma_f32_16x16x32_bf16(
                        af[m], bfr[n], acc[m][n], 0, 0, 0);
        }
    }

    // store fp32 partial, linear [rw][cw] within this ks quarter
    float* __restrict__ P = Pout + (size_t)ks * 4194304;
    const int rbase = row0 + wr * 64;
    const int cbase = col0 + wc * (BN / 2);
#pragma unroll
    for (int m = 0; m < 4; m++)
#pragma unroll
        for (int n = 0; n < NF; n++) {
            const int cw = cbase + n * 16 + lr;
#pragma unroll
            for (int j = 0; j < 4; j++) {
                const int rw = rbase + m * 16 + (l >> 4) * 4 + j;
                P[(size_t)rw * 1024 + cw] = acc[m][n][j];
            }
        }
}

// ---------------------------------------------------------------------------
// reduce the four split-K partials + bias (inverse col-permute) and scatter
// to the NHWC fp32 output.
// ---------------------------------------------------------------------------
__global__ __launch_bounds__(256) void k_redscatter(const float* __restrict__ P,
                                                    const float* __restrict__ bo,
                                                    float* __restrict__ Y)
{
    const int i = (blockIdx.x * 256 + threadIdx.x) * 4;   // 0..4194300
    const int rw = i >> 10, cw = i & 1023;
    const f32x4 v0 = *(const f32x4*)(P + i);
    const f32x4 v1 = *(const f32x4*)(P + 4194304 + i);
    const f32x4 v2 = *(const f32x4*)(P + 8388608 + i);
    const f32x4 v3 = *(const f32x4*)(P + 12582912 + i);
    const int p0 = cw >> 7, low = cw & 127;
    const int b = rw >> 10, hh = (rw >> 5) & 31, wwp = rw & 31;
    float* dst = Y + (size_t)(b * 256 + hh * 8 + p0) * 4096 + wwp * 128 + low;
    f32x4 o;
#pragma unroll
    for (int j = 0; j < 4; j++) {
        const int c = cw + j;
        o[j] = (v0[j] + v1[j]) + (v2[j] + v3[j])
             + bo[((c & 15) << 6) + ((c >> 7) << 3) + ((c >> 4) & 7)];
    }
    *(f32x4*)dst = o;
}

// ---------------------------------------------------------------------------
// Per (patch, head): 8x8 circular conv per channel, LN, v-mult -> Z bf16
// ---------------------------------------------------------------------------
__global__ __launch_bounds__(128) void k_freqconv(const __bf16* __restrict__ C1,
                                                  const float* __restrict__ lns,
                                                  const float* __restrict__ lnb,
                                                  __bf16* __restrict__ Z)
{
    const int blk = blockIdx.x;          // 0..16383
    const int p = blk >> 2, head = blk & 3;
    const int t = threadIdx.x;           // 0..127

    __shared__ float qs[16 * 68];
    __shared__ float ks[16 * 68];
    __shared__ float vs[16 * 68];
    __shared__ float os[16 * 68];

    const __bf16* __restrict__ base = C1 + (size_t)p * 12288 + head * 1024;
    {
        const int cl = t >> 3, off = (t & 7) * 8;
        const bf16x8 vq = *(const bf16x8*)(base + cl * 64 + off);
        const bf16x8 vk = *(const bf16x8*)(base + 4096 + cl * 64 + off);
        const bf16x8 vv = *(const bf16x8*)(base + 8192 + cl * 64 + off);
#pragma unroll
        for (int e = 0; e < 8; e++) {
            qs[cl * 68 + off + e] = (float)vq[e];
            ks[cl * 68 + off + e] = (float)vk[e];
            vs[cl * 68 + off + e] = (float)vv[e];
        }
    }
    __syncthreads();

    const int cc = t >> 3, p0 = t & 7;
    float outr[8] = {0.f, 0.f, 0.f, 0.f, 0.f, 0.f, 0.f, 0.f};
#pragma unroll
    for (int i0 = 0; i0 < 8; i0++) {
        const int kr = (p0 - i0) & 7;
        const f32x4 qa = *(const f32x4*)&qs[cc * 68 + i0 * 8];
        const f32x4 qb = *(const f32x4*)&qs[cc * 68 + i0 * 8 + 4];
        const f32x4 ka = *(const f32x4*)&ks[cc * 68 + kr * 8];
        const f32x4 kb = *(const f32x4*)&ks[cc * 68 + kr * 8 + 4];
        const float qrow[8] = {qa[0], qa[1], qa[2], qa[3], qb[0], qb[1], qb[2], qb[3]};
        const float krow[8] = {ka[0], ka[1], ka[2], ka[3], kb[0], kb[1], kb[2], kb[3]};
#pragma unroll
        for (int j = 0; j < 8; j++) {
            const float qv = qrow[j];
#pragma unroll
            for (int p1 = 0; p1 < 8; p1++)
                outr[p1] = fmaf(qv, krow[(p1 - j) & 7], outr[p1]);
        }
    }
#pragma unroll
    for (int e = 0; e < 8; e++)
        os[cc * 68 + p0 * 8 + e] = outr[e];
    __syncthreads();

    if (t < 64) {
        const int pp = t;
        float o[16];
        float mu = 0.f;
#pragma unroll
        for (int c2 = 0; c2 < 16; c2++) { o[c2] = os[c2 * 68 + pp]; mu += o[c2]; }
        mu *= 0.0625f;
        float var = 0.f;
#pragma unroll
        for (int c2 = 0; c2 < 16; c2++) { const float d = o[c2] - mu; var = fmaf(d, d, var); }
        var *= 0.0625f;
        const float rs = rsqrtf(var + 1e-6f);
        bf16x8 z0, z1;
#pragma unroll
        for (int c2 = 0; c2 < 16; c2++) {
            float zv = (o[c2] - mu) * rs * lns[c2] + lnb[c2];
            zv *= vs[c2 * 68 + pp];
            if (c2 < 8) z0[c2] = (__bf16)zv; else z1[c2 - 8] = (__bf16)zv;
        }
        bf16x8* zp = (bf16x8*)(Z + (size_t)p * 4096 + pp * 64 + head * 16);
        zp[0] = z0;
        zp[1] = z1;
    }
}

// ---------------------------------------------------------------------------
extern "C" void kernel_launch(void* const* d_in, const int* in_sizes, int n_in,
                              void* d_out, int out_size, void* d_ws, size_t ws_size,
                              hipStream_t stream)
{
    const float* x   = (const float*)d_in[0];
    const float* Wq  = (const float*)d_in[1];
    const float* bq  = (const float*)d_in[2];
    const float* Wk  = (const float*)d_in[3];
    const float* bk  = (const float*)d_in[4];
    const float* Wv  = (const float*)d_in[5];
    const float* bv  = (const float*)d_in[6];
    const float* lns = (const float*)d_in[7];
    const float* lnb = (const float*)d_in[8];
    const float* Wo  = (const float*)d_in[9];
    const float* bo  = (const float*)d_in[10];
    float* out = (float*)d_out;

    char* ws = (char*)d_ws;
    __bf16* Xb    = (__bf16*)(ws);                       //  8,388,608 B
    __bf16* WqkvT = (__bf16*)(ws + 8388608);             // 25,165,824 B
    float*  bperm = (float*) (ws + 33554432);            //     49,152 B
    __bf16* WoutT = (__bf16*)(ws + 33603584);            //  8,388,608 B
    __bf16* C1    = (__bf16*)(ws + 41992192);            // 100,663,296 B
    __bf16* Z     = (__bf16*)(ws + 142655488);           // 33,554,432 B  -> 176,209,920 total
    // split-K partials alias the C1 region (dead after k_freqconv): 4x16.8MB
    float*  Ppart = (float*) (ws + 41992192);            // 67,108,864 B (within C1's 100MB)

    // merged layout / dtype conversions (single dispatch)
    k_prep<<<dim3(5424), dim3(256), 0, stream>>>(x, Wq, Wk, Wv, bq, bk, bv, Wo,
                                                 Xb, WqkvT, bperm, WoutT);

    // QKV projection GEMM: [4096,1024] x [1024,12288] -> C1 bf16
    // (2-phase 128^2, 2 blocks/CU for inter-block TLP)
    gemm128<<<dim3(3072), dim3(256), 0, stream>>>(Xb, WqkvT, C1, bperm,
                                                  4096, 12288, 1024, 32);

    // per-patch circular conv + LN + v-mult -> Z bf16 [4096, 4096]
    k_freqconv<<<dim3(16384), dim3(128), 0, stream>>>(C1, lns, lnb, Z);

    // output projection GEMM, split-K=4 -> fp32 partials (in dead C1 region)
    gemm_splitk<128><<<dim3(1024), dim3(256), 0, stream>>>(Z, WoutT, Ppart,
                                                           4096, 1024);

    // reduce partials + bias, scatter to NHWC fp32 output
    k_redscatter<<<dim3(4096), dim3(256), 0, stream>>>(Ppart, bo, out);
}

// Round 13
// 226.960 us; speedup vs baseline: 1.0666x; 1.0666x over previous
//
#include <hip/hip_runtime.h>
#include <hip/hip_bf16.h>
#include <cstdint>
#include <cstddef>

typedef float  f32x4  __attribute__((ext_vector_type(4)));
typedef __bf16 bf16x8 __attribute__((ext_vector_type(8)));
typedef __bf16 bf16x4 __attribute__((ext_vector_type(4)));

// Problem constants
// B=4, H=W=256, Cin=16, P=8, DIM=16, HEADS=4
// patches: 4*32*32 = 4096, K1 = 8*8*16 = 1024, N1 = 3*4096 = 12288
// Z: [4096, 4096], Wout: [4096, 1024]

#define GLOAD_LDS16(gp, lp)                                                     \
    __builtin_amdgcn_global_load_lds(                                           \
        (const __attribute__((address_space(1))) void*)(gp),                    \
        (__attribute__((address_space(3))) void*)(lp), 16, 0, 0)

#define MFMA16(d, a, b) d = __builtin_amdgcn_mfma_f32_16x16x32_bf16(a, b, d, 0, 0, 0)

// s_barrier with compile-time memory ordering (raw builtin is NOT a fence)
#define BAR() asm volatile("s_barrier" ::: "memory")

// ---------------------------------------------------------------------------
// merged prep kernel: one dispatch, block-range dispatch to 4 sub-kernels.
//  [0,4096)        im2col   x -> Xb
//  [4096,4864)     wqkvT    Wq/Wk/Wv -> WqkvT (permuted, transposed, bf16)
//  [4864,4912)     biasperm bq/bk/bv -> bperm
//  [4912,5424)     woutT    Wout -> WoutT (col-permuted, transposed, bf16)
// ---------------------------------------------------------------------------
__global__ __launch_bounds__(256) void k_prep(const float* __restrict__ x,
                                              const float* __restrict__ Wq,
                                              const float* __restrict__ Wk,
                                              const float* __restrict__ Wv,
                                              const float* __restrict__ bq,
                                              const float* __restrict__ bk,
                                              const float* __restrict__ bv,
                                              const float* __restrict__ Wo,
                                              __bf16* __restrict__ Xb,
                                              __bf16* __restrict__ WT,
                                              float* __restrict__ bp,
                                              __bf16* __restrict__ WoT)
{
    __shared__ float smem[64 * 261];     // 66816 B; reused by wqkvT/woutT
    const int blk = (int)blockIdx.x;
    const int t = threadIdx.x;

    if (blk < 4096) {
        // ---- im2col ----
        const int p = blk;
        const int b = p >> 10, hh = (p >> 5) & 31, ww = p & 31;
        const int e = t * 4;
        const int c = e & 15, ij = e >> 4;
        const int i = ij >> 3, j = ij & 7;
        const size_t src = ((((size_t)(b * 256 + hh * 8 + i)) * 256) + (ww * 8 + j)) * 16 + c;
        f32x4 v = *(const f32x4*)(x + src);
        bf16x4 o;
        o[0] = (__bf16)v[0]; o[1] = (__bf16)v[1]; o[2] = (__bf16)v[2]; o[3] = (__bf16)v[3];
        *(bf16x4*)(Xb + (size_t)p * 1024 + e) = o;
    } else if (blk < 4864) {
        // ---- wqkvT ----
        int q = blk - 4096;
        const int kb = q & 15;   q >>= 4;
        const int ch = q & 15;   q >>= 4;
        const int s  = q;
        const int k0 = kb * 64;
        const float* __restrict__ W = (s == 0) ? Wq : (s == 1) ? Wk : Wv;
#pragma unroll
        for (int rep = 0; rep < 16; rep++) {
            const int idx = rep * 256 + t;
            const int kl = idx >> 6, col4 = (idx & 63) * 4;
            const f32x4 v = *(const f32x4*)(W + (size_t)(k0 + kl) * 4096 + ch * 256 + col4);
            smem[kl * 261 + col4 + 0] = v[0];
            smem[kl * 261 + col4 + 1] = v[1];
            smem[kl * 261 + col4 + 2] = v[2];
            smem[kl * 261 + col4 + 3] = v[3];
        }
        __syncthreads();
        const size_t nbase = (size_t)s * 4096 + ch * 64;
#pragma unroll
        for (int rep = 0; rep < 64; rep++) {
            const int idx = rep * 256 + t;
            const int kl = idx & 63;
            const int rest = idx >> 6;
            const int p = rest & 63, h = rest >> 6;
            WT[(nbase + h * 1024 + p) * 1024 + k0 + kl] = (__bf16)smem[kl * 261 + p * 4 + h];
        }
    } else if (blk < 4912) {
        // ---- biasperm ----
        const int n = (blk - 4864) * 256 + t;
        const int s = n >> 12;
        const int r = n & 4095;
        const int head = r >> 10, c = (r >> 6) & 15, pp = r & 63;
        const float* __restrict__ b = (s == 0) ? bq : (s == 1) ? bk : bv;
        bp[n] = b[c * 256 + pp * 4 + head];
    } else {
        // ---- woutT ----
        const int q = blk - 4912;
        const int n0 = (q & 15) * 64;
        const int k0 = (q >> 4) * 128;
        const int ch = n0 >> 6;
#pragma unroll
        for (int rep = 0; rep < 32; rep++) {
            const int idx = rep * 256 + t;
            const int kl = idx >> 6, nn = idx & 63;
            smem[nn * 129 + kl] = Wo[(size_t)(k0 + kl) * 1024 + n0 + nn];
        }
        __syncthreads();
#pragma unroll
        for (int rep = 0; rep < 32; rep++) {
            const int idx = rep * 256 + t;
            const int nn = idx >> 7, kl = idx & 127;
            const int no = ((nn >> 3) & 7) * 128 + (nn & 7) * 16 + ch;
            WoT[(size_t)no * 4096 + k0 + kl] = (__bf16)smem[nn * 129 + kl];
        }
    }
}

// ---------------------------------------------------------------------------
// 256x256 bf16 GEMM, v4 (frozen): TWO phases per K-tile.
// 512 thr = 8 waves (2M x 4N), wave tile 128x64, BK=64, dbuf LDS 128 KB.
//  p1: read b(t)[8] + a1(t)[8]; stage B(t+1); 32 MFMA (a0 x b -> acc[0..3]);
//      vmcnt(4) retires A(t+1)   [FIFO: A(t+1)@p2(t-1), B(t+1)@p1(t)]
//  p2: read a0(t+1)[8]; stage A(t+2); 32 MFMA (a1 x b -> acc[4..7]);
//      vmcnt(4) retires B(t+1).
// ---------------------------------------------------------------------------
__device__ __forceinline__ void stage_half(const __bf16* __restrict__ mat,
                                           const int gRow0, const int K,
                                           const int k0, __bf16* lds, const int t)
{
    const int w6 = (t >> 6) << 6;                    // wave-uniform lane base
#pragma unroll
    for (int r = 0; r < 2; r++) {
        const int idx = r * 512 + t;                 // 0..1023 (16B chunks)
        const int row = idx >> 3;                    // 0..127
        const int colb = ((t & 7) << 4) ^ ((row & 7) << 4);
        const char* gp = (const char*)(mat + (size_t)(gRow0 + row) * K + k0) + colb;
        GLOAD_LDS16(gp, (char*)lds + (size_t)(r * 512 + w6) * 16);
    }
}

__global__ __launch_bounds__(512, 1) void gemm256(const __bf16* __restrict__ A,
                                                  const __bf16* __restrict__ Bt,
                                                  __bf16* __restrict__ C,
                                                  const float* __restrict__ bias,
                                                  const int M, const int N,
                                                  const int K, const int nby)
{
    __shared__ __bf16 As[2][256 * 64];
    __shared__ __bf16 Bs[2][256 * 64];

    const int t = threadIdx.x;
    const int l = t & 63, w = t >> 6;
    const int wr = w >> 2, wc = w & 3;               // 2 x 4 wave grid

    // XCD-aware bijective swizzle; column-major (bm fast) for B L2 locality
    const int nwg = (int)gridDim.x, cpx = nwg >> 3;
    const int bid = (int)blockIdx.x;
    const int sbid = (bid & 7) * cpx + (bid >> 3);
    const int bm = sbid % nby, bn = sbid / nby;
    const int row0 = bm * 256, col0 = bn * 256;

    const int lrow = l & 15;
    const int lkb  = (l >> 4) << 4;                  // k-group byte offset
    const int lswz = (l & 7) << 4;
    const int ce0 = ((0  + lkb) ^ lswz) >> 1;        // element col, kk=0
    const int ce1 = ((64 + lkb) ^ lswz) >> 1;        // element col, kk=1

    const int arow = wr * 128 + lrow;
    const int brow = wc * 64 + lrow;

    const int NT = K >> 6;
    f32x4 acc[8][4] = {};
    bf16x8 a0[4][2], a1[4][2], b[4][2];

    // prologue: A(0),A(1),B(0) staged; drain; pre-read a0(0)
    stage_half(A,  row0,       K, 0,  As[0],        t);
    stage_half(A,  row0 + 128, K, 0,  As[0] + 8192, t);
    stage_half(A,  row0,       K, 64, As[1],        t);
    stage_half(A,  row0 + 128, K, 64, As[1] + 8192, t);
    stage_half(Bt, col0,       K, 0,  Bs[0],        t);
    stage_half(Bt, col0 + 128, K, 0,  Bs[0] + 8192, t);
    asm volatile("s_waitcnt vmcnt(0)" ::: "memory");
    BAR();
#pragma unroll
    for (int mi = 0; mi < 4; ++mi) {
        const int rr = (arow + mi * 16) * 64;
        a0[mi][0] = *(const bf16x8*)&As[0][rr + ce0];
        a0[mi][1] = *(const bf16x8*)&As[0][rr + ce1];
    }

    int cur = 0;
    for (int it = 0; it < NT; ++it) {
        const __bf16* AsC = As[cur];
        const __bf16* AsN = As[cur ^ 1];
        const __bf16* BsC = Bs[cur];
        __bf16* BsN = Bs[cur ^ 1];
        const bool stB = (it + 1 < NT);      // stage B(t+1) -> Bs[cur^1]
        const bool stA = (it + 2 < NT);      // stage A(t+2) -> As[cur]
        const bool pfA = (it + 1 < NT);      // prefetch a0(t+1) from As[cur^1]
        const int kB = (it + 1) << 6;
        const int kA = (it + 2) << 6;

        // ---- p1: acc[0..3] += a0 x b ; stage B(t+1) ; F1 ----------------
        BAR();
#pragma unroll
        for (int ni = 0; ni < 4; ++ni) {
            const int rr = (brow + ni * 16) * 64;
            b[ni][0] = *(const bf16x8*)&BsC[rr + ce0];
            b[ni][1] = *(const bf16x8*)&BsC[rr + ce1];
        }
#pragma unroll
        for (int mi = 0; mi < 4; ++mi) {
            const int rr = (arow + 64 + mi * 16) * 64;
            a1[mi][0] = *(const bf16x8*)&AsC[rr + ce0];
            a1[mi][1] = *(const bf16x8*)&AsC[rr + ce1];
        }
        if (stB) {
            stage_half(Bt, col0,       K, kB, BsN,        t);
            stage_half(Bt, col0 + 128, K, kB, BsN + 8192, t);
        }
        __builtin_amdgcn_s_setprio(1);
#pragma unroll
        for (int mi = 0; mi < 4; ++mi)
#pragma unroll
            for (int ni = 0; ni < 4; ++ni) {
                MFMA16(acc[mi][ni], a0[mi][0], b[ni][0]);
                MFMA16(acc[mi][ni], a0[mi][1], b[ni][1]);
            }
        __builtin_amdgcn_s_setprio(0);
        if (pfA)   // A(t+1) resident before p2's prefetch reads
            asm volatile("s_waitcnt vmcnt(4)" ::: "memory");

        // ---- p2: acc[4..7] += a1 x b ; prefetch a0(t+1) ; stage A(t+2) --
        BAR();
        if (pfA) {
#pragma unroll
            for (int mi = 0; mi < 4; ++mi) {
                const int rr = (arow + mi * 16) * 64;
                a0[mi][0] = *(const bf16x8*)&AsN[rr + ce0];
                a0[mi][1] = *(const bf16x8*)&AsN[rr + ce1];
            }
        }
        if (stA) {
            stage_half(A, row0,       K, kA, As[cur],        t);
            stage_half(A, row0 + 128, K, kA, As[cur] + 8192, t);
        }
        __builtin_amdgcn_s_setprio(1);
#pragma unroll
        for (int mi = 0; mi < 4; ++mi)
#pragma unroll
            for (int ni = 0; ni < 4; ++ni) {
                MFMA16(acc[4 + mi][ni], a1[mi][0], b[ni][0]);
                MFMA16(acc[4 + mi][ni], a1[mi][1], b[ni][1]);
            }
        __builtin_amdgcn_s_setprio(0);
        if (stB) {  // B(t+1) resident before next p1's b reads
            if (stA) asm volatile("s_waitcnt vmcnt(4)" ::: "memory");
            else     asm volatile("s_waitcnt vmcnt(0)" ::: "memory");
        }

        cur ^= 1;
    }

    // epilogue: C += bias, bf16
    const int rbase = row0 + wr * 128;
    const int cbase = col0 + wc * 64;
    const int jr = (l >> 4) * 4;
#pragma unroll
    for (int m = 0; m < 8; ++m)
#pragma unroll
        for (int n = 0; n < 4; ++n) {
            const int cw = cbase + n * 16 + lrow;
            const float bsv = bias[cw];
#pragma unroll
            for (int j = 0; j < 4; ++j) {
                const int rw = rbase + m * 16 + jr + j;
                C[(size_t)rw * N + cw] = (__bf16)(acc[m][n][j] + bsv);
            }
        }
}

// ---------------------------------------------------------------------------
// gemm2 split-K=4: 128x128 glds GEMM, 1024 blocks = (bm 32, ks 4, bn 8).
// Each block does K/4 = 1024 and stores fp32 partial P[ks][4096][1024].
// 4 blocks/CU resident -> TLP hides the 2-phase vmcnt(0) drains.
// ---------------------------------------------------------------------------
template <int BN>
__global__ __launch_bounds__(256, 4) void gemm_splitk(const __bf16* __restrict__ A,
                                                      const __bf16* __restrict__ Bt,
                                                      float* __restrict__ Pout,
                                                      const int K, const int kc)
{
    constexpr int BM  = 128, BK = 64;
    constexpr int NF  = BN / 32;
    constexpr int APW = (BM * BK / 512) / 4;
    constexpr int BPW = (BN * BK / 512) / 4;
    __shared__ __bf16 As[BM * BK];
    __shared__ __bf16 Bs[BN * BK];

    const int t = threadIdx.x;
    const int l = t & 63, w = t >> 6;

    const int nwg  = (int)gridDim.x;
    const int cpx  = nwg >> 3;
    const int bid  = (int)blockIdx.x;
    const int sbid = (bid & 7) * cpx + (bid >> 3);
    const int bm = sbid >> 5;                // 0..31
    const int ks = (sbid >> 3) & 3;          // 0..3
    const int bn = sbid & 7;                 // 0..7
    const int row0 = bm * BM, col0 = bn * BN;
    const int kstart = ks * kc;

    const int wr = w >> 1, wc = w & 1;
    const int lr = l & 15;
    const int lk = (l >> 4) * 8;
    const int srow = l >> 3;
    const int scol = (l & 7) * 8;

    f32x4 acc[4][NF] = {};

    for (int k0 = kstart; k0 < kstart + kc; k0 += BK) {
        __syncthreads();
#pragma unroll
        for (int p = 0; p < APW; p++) {
            const int chunk = w * APW + p;
            const __bf16* gp = A + (size_t)(row0 + chunk * 8 + srow) * K + k0 + scol;
            GLOAD_LDS16(gp, &As[chunk * 512]);
        }
#pragma unroll
        for (int p = 0; p < BPW; p++) {
            const int chunk = w * BPW + p;
            const __bf16* gp = Bt + (size_t)(col0 + chunk * 8 + srow) * K + k0 + scol;
            GLOAD_LDS16(gp, &Bs[chunk * 512]);
        }
        __syncthreads();
#pragma unroll
        for (int kk = 0; kk < 2; kk++) {
            bf16x8 af[4], bfr[NF];
#pragma unroll
            for (int m = 0; m < 4; m++)
                af[m] = *(const bf16x8*)&As[(wr * 64 + m * 16 + lr) * BK + kk * 32 + lk];
#pragma unroll
            for (int n = 0; n < NF; n++)
                bfr[n] = *(const bf16x8*)&Bs[(wc * (BN / 2) + n * 16 + lr) * BK + kk * 32 + lk];
#pragma unroll
            for (int m = 0; m < 4; m++)
#pragma unroll
                for (int n = 0; n < NF; n++)
                    acc[m][n] = __builtin_amdgcn_mfma_f32_16x16x32_bf16(
                        af[m], bfr[n], acc[m][n], 0, 0, 0);
        }
    }

    // store fp32 partial, linear [rw][cw] within this ks quarter
    float* __restrict__ P = Pout + (size_t)ks * 4194304;
    const int rbase = row0 + wr * 64;
    const int cbase = col0 + wc * (BN / 2);
#pragma unroll
    for (int m = 0; m < 4; m++)
#pragma unroll
        for (int n = 0; n < NF; n++) {
            const int cw = cbase + n * 16 + lr;
#pragma unroll
            for (int j = 0; j < 4; j++) {
                const int rw = rbase + m * 16 + (l >> 4) * 4 + j;
                P[(size_t)rw * 1024 + cw] = acc[m][n][j];
            }
        }
}

// ---------------------------------------------------------------------------
// reduce the four split-K partials + bias (inverse col-permute) and scatter
// to the NHWC fp32 output.
// ---------------------------------------------------------------------------
__global__ __launch_bounds__(256) void k_redscatter(const float* __restrict__ P,
                                                    const float* __restrict__ bo,
                                                    float* __restrict__ Y)
{
    const int i = (blockIdx.x * 256 + threadIdx.x) * 4;   // 0..4194300
    const int rw = i >> 10, cw = i & 1023;
    const f32x4 v0 = *(const f32x4*)(P + i);
    const f32x4 v1 = *(const f32x4*)(P + 4194304 + i);
    const f32x4 v2 = *(const f32x4*)(P + 8388608 + i);
    const f32x4 v3 = *(const f32x4*)(P + 12582912 + i);
    const int p0 = cw >> 7, low = cw & 127;
    const int b = rw >> 10, hh = (rw >> 5) & 31, wwp = rw & 31;
    float* dst = Y + (size_t)(b * 256 + hh * 8 + p0) * 4096 + wwp * 128 + low;
    f32x4 o;
#pragma unroll
    for (int j = 0; j < 4; j++) {
        const int c = cw + j;
        o[j] = (v0[j] + v1[j]) + (v2[j] + v3[j])
             + bo[((c & 15) << 6) + ((c >> 7) << 3) + ((c >> 4) & 7)];
    }
    *(f32x4*)dst = o;
}

// ---------------------------------------------------------------------------
// Per (patch, head): 8x8 circular conv per channel, LN, v-mult -> Z bf16
// ---------------------------------------------------------------------------
__global__ __launch_bounds__(128) void k_freqconv(const __bf16* __restrict__ C1,
                                                  const float* __restrict__ lns,
                                                  const float* __restrict__ lnb,
                                                  __bf16* __restrict__ Z)
{
    const int blk = blockIdx.x;          // 0..16383
    const int p = blk >> 2, head = blk & 3;
    const int t = threadIdx.x;           // 0..127

    __shared__ float qs[16 * 68];
    __shared__ float ks[16 * 68];
    __shared__ float vs[16 * 68];
    __shared__ float os[16 * 68];

    const __bf16* __restrict__ base = C1 + (size_t)p * 12288 + head * 1024;
    {
        const int cl = t >> 3, off = (t & 7) * 8;
        const bf16x8 vq = *(const bf16x8*)(base + cl * 64 + off);
        const bf16x8 vk = *(const bf16x8*)(base + 4096 + cl * 64 + off);
        const bf16x8 vv = *(const bf16x8*)(base + 8192 + cl * 64 + off);
#pragma unroll
        for (int e = 0; e < 8; e++) {
            qs[cl * 68 + off + e] = (float)vq[e];
            ks[cl * 68 + off + e] = (float)vk[e];
            vs[cl * 68 + off + e] = (float)vv[e];
        }
    }
    __syncthreads();

    const int cc = t >> 3, p0 = t & 7;
    float outr[8] = {0.f, 0.f, 0.f, 0.f, 0.f, 0.f, 0.f, 0.f};
#pragma unroll
    for (int i0 = 0; i0 < 8; i0++) {
        const int kr = (p0 - i0) & 7;
        const f32x4 qa = *(const f32x4*)&qs[cc * 68 + i0 * 8];
        const f32x4 qb = *(const f32x4*)&qs[cc * 68 + i0 * 8 + 4];
        const f32x4 ka = *(const f32x4*)&ks[cc * 68 + kr * 8];
        const f32x4 kb = *(const f32x4*)&ks[cc * 68 + kr * 8 + 4];
        const float qrow[8] = {qa[0], qa[1], qa[2], qa[3], qb[0], qb[1], qb[2], qb[3]};
        const float krow[8] = {ka[0], ka[1], ka[2], ka[3], kb[0], kb[1], kb[2], kb[3]};
#pragma unroll
        for (int j = 0; j < 8; j++) {
            const float qv = qrow[j];
#pragma unroll
            for (int p1 = 0; p1 < 8; p1++)
                outr[p1] = fmaf(qv, krow[(p1 - j) & 7], outr[p1]);
        }
    }
#pragma unroll
    for (int e = 0; e < 8; e++)
        os[cc * 68 + p0 * 8 + e] = outr[e];
    __syncthreads();

    if (t < 64) {
        const int pp = t;
        float o[16];
        float mu = 0.f;
#pragma unroll
        for (int c2 = 0; c2 < 16; c2++) { o[c2] = os[c2 * 68 + pp]; mu += o[c2]; }
        mu *= 0.0625f;
        float var = 0.f;
#pragma unroll
        for (int c2 = 0; c2 < 16; c2++) { const float d = o[c2] - mu; var = fmaf(d, d, var); }
        var *= 0.0625f;
        const float rs = rsqrtf(var + 1e-6f);
        bf16x8 z0, z1;
#pragma unroll
        for (int c2 = 0; c2 < 16; c2++) {
            float zv = (o[c2] - mu) * rs * lns[c2] + lnb[c2];
            zv *= vs[c2 * 68 + pp];
            if (c2 < 8) z0[c2] = (__bf16)zv; else z1[c2 - 8] = (__bf16)zv;
        }
        bf16x8* zp = (bf16x8*)(Z + (size_t)p * 4096 + pp * 64 + head * 16);
        zp[0] = z0;
        zp[1] = z1;
    }
}

// ---------------------------------------------------------------------------
extern "C" void kernel_launch(void* const* d_in, const int* in_sizes, int n_in,
                              void* d_out, int out_size, void* d_ws, size_t ws_size,
                              hipStream_t stream)
{
    const float* x   = (const float*)d_in[0];
    const float* Wq  = (const float*)d_in[1];
    const float* bq  = (const float*)d_in[2];
    const float* Wk  = (const float*)d_in[3];
    const float* bk  = (const float*)d_in[4];
    const float* Wv  = (const float*)d_in[5];
    const float* bv  = (const float*)d_in[6];
    const float* lns = (const float*)d_in[7];
    const float* lnb = (const float*)d_in[8];
    const float* Wo  = (const float*)d_in[9];
    const float* bo  = (const float*)d_in[10];
    float* out = (float*)d_out;

    char* ws = (char*)d_ws;
    __bf16* Xb    = (__bf16*)(ws);                       //  8,388,608 B
    __bf16* WqkvT = (__bf16*)(ws + 8388608);             // 25,165,824 B
    float*  bperm = (float*) (ws + 33554432);            //     49,152 B
    __bf16* WoutT = (__bf16*)(ws + 33603584);            //  8,388,608 B
    __bf16* C1    = (__bf16*)(ws + 41992192);             // 100,663,296 B
    __bf16* Z     = (__bf16*)(ws + 142655488);           // 33,554,432 B  -> 176,209,920 total
    // split-K partials alias the C1 region (dead after k_freqconv): 4x16.8MB
    float*  Ppart = (float*) (ws + 41992192);            // 67,108,864 B (within C1's 100MB)

    // merged layout / dtype conversions (single dispatch)
    k_prep<<<dim3(5424), dim3(256), 0, stream>>>(x, Wq, Wk, Wv, bq, bk, bv, Wo,
                                                 Xb, WqkvT, bperm, WoutT);

    // QKV projection GEMM: [4096,1024] x [1024,12288] -> C1 bf16 (2-phase 256^2)
    gemm256<<<dim3(768), dim3(512), 0, stream>>>(Xb, WqkvT, C1, bperm,
                                                 4096, 12288, 1024, 16);

    // per-patch circular conv + LN + v-mult -> Z bf16 [4096, 4096]
    k_freqconv<<<dim3(16384), dim3(128), 0, stream>>>(C1, lns, lnb, Z);

    // output projection GEMM, split-K=4 -> fp32 partials (in dead C1 region)
    gemm_splitk<128><<<dim3(1024), dim3(256), 0, stream>>>(Z, WoutT, Ppart,
                                                           4096, 1024);

    // reduce partials + bias, scatter to NHWC fp32 output
    k_redscatter<<<dim3(4096), dim3(256), 0, stream>>>(Ppart, bo, out);
}